// Round 8
// baseline (7547.359 us; speedup 1.0000x reference)
//
#include <hip/hip_runtime.h>

// ---------------------------------------------------------------------------
// MPNODE_STL10 forward, round 8: round-5 verified core + occupancy/staging fix.
//  - Base: round-5 kernel (passed, absmax 2.4e-4). NCHW fp32 state.
//  - Change 1: NW=2 (128-thr blocks, 16x4 wave tiles) for ALL stages ->
//    2-4x more blocks, LDS 29->19KB -> ~2x residency (TLP latency hiding).
//  - Change 2: conv2 staging normalization via per-channel LDS table (sTab),
//    filled once per block (1 rsqrt/channel) instead of per-element global
//    mu/sigma loads + rsqrt. Same values, far less VALU/VMEM.
//  - Everything else identical to round 5: split-bf16 MFMA (weights=A,
//    acts=B), bulk A-loads into VGPRs, dbuf LDS staging, RS=20 stride,
//    fused stats in conv1 epilogue, RK4 update in conv2 epilogue.
// ---------------------------------------------------------------------------

typedef __attribute__((ext_vector_type(8)))  short  s16x8;
typedef __attribute__((ext_vector_type(16))) float  f32x16;

__device__ __forceinline__ unsigned short bf16_rtne(float f) {
    unsigned u = __builtin_bit_cast(unsigned, f);
    unsigned r = u + 0x7FFFu + ((u >> 16) & 1u);
    return (unsigned short)(r >> 16);
}

// ---------------- weight pack (verified rounds 4-5) ------------------------
// Per dir (0=conv, 1=transposed+flipped), per bank(4):
//   [icc(C/16)][mt(C/32)][kp(9)][pl(2: hi,lo)][lane(64)][j(8)]
// A element: m = lane&31 -> oc, k = (lane>>5)*8+j -> ic within chunk.
__global__ __launch_bounds__(256) void pack_weights(
    const float* __restrict__ Wb, unsigned short* __restrict__ out, int C)
{
    const int dir = blockIdx.y;
    const int MT = C >> 5, ICC = C >> 4;
    const size_t TOT = (size_t)36 * C * C;
    size_t t = (size_t)blockIdx.x * 256 + threadIdx.x;
    if (t >= TOT) return;
    int j = t & 7;
    int l = (t >> 3) & 63;
    size_t r = t >> 9;
    int kp  = r % 9;  r /= 9;
    int mt  = r % MT; r /= MT;
    int icc = r % ICC; r /= ICC;
    int bank = (int)r;
    int oc = mt * 32 + (l & 31);
    int ic = icc * 16 + (l >> 5) * 8 + j;
    int kh = kp / 3, kw = kp % 3;
    float v;
    if (dir == 0)
        v = Wb[(((size_t)(bank * C + oc) * C + ic) * 3 + kh) * 3 + kw];
    else
        v = Wb[(((size_t)(bank * C + ic) * C + oc) * 3 + (2 - kh)) * 3 + (2 - kw)];
    unsigned short h = bf16_rtne(v);
    float hf = __builtin_bit_cast(float, (unsigned)h << 16);
    unsigned short lo = bf16_rtne(v - hf);
    size_t idx = ((((size_t)bank * ICC + icc) * MT + mt) * 9 + kp) * 1024 + l * 8 + j;
    unsigned short* base = out + (size_t)dir * 72 * C * C;
    base[idx] = h;
    base[idx + 512] = lo;
}

// ---------------- MFMA conv kernel (round-5 core) --------------------------
template<int NW, bool CONV2>
__global__ __launch_bounds__(NW * 64) void conv_mfma4(
    const float* __restrict__ in,
    const unsigned short* __restrict__ pA,
    const float* __restrict__ bias,
    const float* __restrict__ sums_in,       // conv2: [s | ss], 2*NCtot floats
    float* __restrict__ sums_out,            // conv1: accumulate; conv2: zero
    const float* __restrict__ ybase, float* __restrict__ accb,
    float* __restrict__ ydst,
    int C, int H, int W, int tilesX, int NCtot, float inv_hw,
    int mode, float acoef, float dt6)
{
    constexpr int TPX = 16, TPY = 2 * NW;
    constexpr int HX = TPX + 2, HY = TPY + 2;
    constexpr int NROW = HX * HY;
    constexpr int RS = 20;               // row stride (shorts), 40B
    constexpr int PL = NROW * RS;
    constexpr int BUFS = 2 * PL;         // hi plane + lo plane
    constexpr int NTHR = NW * 64;
    constexpr int NELEM = NROW * 16;
    constexpr int NIT = (NELEM + NTHR - 1) / NTHR;
    __shared__ __align__(16) unsigned short sB[2 * BUFS];
    __shared__ float sTab[CONV2 ? 512 : 4];

    const int tid = threadIdx.x;
    const int w = tid >> 6, lane = tid & 63;
    const int tileX = blockIdx.x % tilesX, tileY = blockIdx.x / tilesX;
    const int px0 = tileX * TPX, py0 = tileY * TPY;
    const int n = blockIdx.z;
    const int mt = blockIdx.y;
    const int ocb = mt * 32;
    const int HW = H * W;
    const int ICC = C >> 4, MT = C >> 5;
    const int col = lane & 31, half = lane >> 5;
    const int xl = col & 15, yr = col >> 4;
    const int wy0 = 2 * w;
    const int ncbase = n * C;

    // conv2: zero the *other* ping-pong sum buffer for the next conv1
    if (CONV2 && blockIdx.x == 0 && blockIdx.z == 0) {
        int per = (2 * NCtot + MT - 1) / MT;
        int st = mt * per;
        int en = st + per; if (en > 2 * NCtot) en = 2 * NCtot;
        for (int i = st + tid; i < en; i += NTHR) sums_out[i] = 0.f;
    }
    // conv2: per-channel mu/rstd table for this n (one rsqrt per channel)
    if (CONV2) {
        for (int c0 = tid; c0 < C; c0 += NTHR) {
            float s = sums_in[ncbase + c0];
            float q = sums_in[NCtot + ncbase + c0];
            float m = s * inv_hw;
            sTab[2 * c0] = m;
            sTab[2 * c0 + 1] = rsqrtf(fmaf(-m, m, q * inv_hw) + 1e-5f);
        }
        __syncthreads();
    }

    float stg[NIT];
    auto stageLoad = [&](int icc) {
#pragma unroll
        for (int i = 0; i < NIT; i++) {
            int e = tid + i * NTHR;
            float v = 0.f;
            if (e < NELEM) {
                int ic = e / NROW; int r = e - ic * NROW;
                int yy = r / HX, xx = r - yy * HX;
                int gy = py0 + yy - 1, gx = px0 + xx - 1;
                if (gy >= 0 && gy < H && gx >= 0 && gx < W) {
                    int c = icc * 16 + ic;
                    v = in[(size_t)(ncbase + c) * HW + gy * W + gx];
                    if (CONV2)
                        v = (v - sTab[2 * c]) * sTab[2 * c + 1];
                }
            }
            stg[i] = v;
        }
    };
    auto stageWrite = [&](int b) {
#pragma unroll
        for (int i = 0; i < NIT; i++) {
            int e = tid + i * NTHR;
            if (e < NELEM) {
                int ic = e / NROW; int r = e - ic * NROW;
                unsigned short h = bf16_rtne(stg[i]);
                float hf = __builtin_bit_cast(float, (unsigned)h << 16);
                unsigned short lo = bf16_rtne(stg[i] - hf);
                int off = b * BUFS + r * RS + ic;
                sB[off] = h;
                sB[off + PL] = lo;
            }
        }
    };
    auto loadB = [&](int b, int kp, s16x8& oh, s16x8& ol) {
        int kh = kp / 3, kw = kp - kh * 3;
        int px = (wy0 + yr + kh) * HX + (xl + kw);
        int off = b * BUFS + px * RS + half * 8;
        oh = *(const s16x8*)&sB[off];
        ol = *(const s16x8*)&sB[off + PL];
    };

    f32x16 accA{}, accB{}, accC{};

    stageLoad(0);
    stageWrite(0);
    __syncthreads();

    for (int icc = 0; icc < ICC; ++icc) {
        // ---- bulk A loads: whole chunk's 9 kp hi+lo into regs ----
        s16x8 aH[9], aL[9];
        {
            const unsigned short* ab =
                pA + ((size_t)(icc * MT + mt)) * 9216 + lane * 8;
#pragma unroll
            for (int kp = 0; kp < 9; ++kp) {
                aH[kp] = *(const s16x8*)(ab + kp * 1024);
                aL[kp] = *(const s16x8*)(ab + kp * 1024 + 512);
            }
        }
        const int b = icc & 1;
        if (icc + 1 < ICC) stageLoad(icc + 1);   // stays outstanding over MFMAs

        s16x8 bh, bl;
        loadB(b, 0, bh, bl);
#pragma unroll
        for (int kp = 0; kp < 9; ++kp) {
            s16x8 bhn, bln;
            if (kp < 8) loadB(b, kp + 1, bhn, bln);
            accA = __builtin_amdgcn_mfma_f32_32x32x16_bf16(aH[kp], bh, accA, 0, 0, 0);
            accB = __builtin_amdgcn_mfma_f32_32x32x16_bf16(aL[kp], bh, accB, 0, 0, 0);
            accC = __builtin_amdgcn_mfma_f32_32x32x16_bf16(aH[kp], bl, accC, 0, 0, 0);
            if (kp < 8) { bh = bhn; bl = bln; }
        }
        if (icc + 1 < ICC) {
            stageWrite(b ^ 1);
            __syncthreads();
        }
    }

    // ---- epilogue: C/D layout col=lane&31, row=(r&3)+8*(r>>2)+4*half ----
    // n-mapping: x = col&15, y = col>>4 -> full 64B-line coalescing.
    const int gx = px0 + xl;
    const int gy = py0 + wy0 + yr;
    const bool valid = (gx < W);
    float* sred = (float*)sB;   // last chunk used buffer 1; buffer 0 free
#pragma unroll
    for (int r = 0; r < 16; r++) {
        int row = (r & 3) + 8 * (r >> 2) + 4 * half;
        int oc = ocb + row;
        size_t idx = (size_t)(ncbase + oc) * HW + (size_t)gy * W + gx;
        float v = accA[r] + accB[r] + accC[r];
        if (!CONV2) {
            v += bias[oc];
            v = fmaxf(v, 0.f);
            if (valid) ydst[idx] = v;
            float s = valid ? v : 0.f;
            float sq = s * s;
#pragma unroll
            for (int m = 1; m < 32; m <<= 1) {
                s  += __shfl_xor(s, m, 64);
                sq += __shfl_xor(sq, m, 64);
            }
            if ((lane & 31) == 0) {
                int slot = ((w * 2 + half) * 16 + r) * 2;
                sred[slot] = s;
                sred[slot + 1] = sq;
            }
        } else if (valid) {
            float k = -v;
            if (mode == 0)      { accb[idx] = k;        ydst[idx] = ybase[idx] + acoef * k; }
            else if (mode == 3) { ydst[idx] = ybase[idx] + dt6 * (accb[idx] + k); }
            else                { accb[idx] += 2.f * k; ydst[idx] = ybase[idx] + acoef * k; }
        }
    }
    if (!CONV2) {
        __syncthreads();
        if (tid < 32) {
            int h2 = (tid >> 2) & 1;
            int r  = (tid & 3) | ((tid >> 3) << 2);
            float s = 0.f, sq = 0.f;
#pragma unroll
            for (int wv = 0; wv < NW; wv++) {
                int slot = ((wv * 2 + h2) * 16 + r) * 2;
                s  += sred[slot];
                sq += sred[slot + 1];
            }
            atomicAdd(&sums_out[ncbase + ocb + tid], s);
            atomicAdd(&sums_out[NCtot + ncbase + ocb + tid], sq);
        }
    }
}

// ---------------- fp32 stem conv (Cin=3) -----------------------------------
#define TS  16
#define OCT 16
#define CIT 8
__global__ __launch_bounds__(256) void conv3x3_kernel(
    const float* __restrict__ in, const float* __restrict__ w,
    const float* __restrict__ bias, float* __restrict__ out,
    int N, int Cin, int Cout, int H, int W, int tilesX, int relu)
{
    __shared__ float sIn[CIT][TS + 2][TS + 2];
    __shared__ float sW[OCT][CIT][9];
    const int tid = threadIdx.x;
    const int tx = tid & (TS - 1), ty = tid >> 4;
    const int tileX = blockIdx.x % tilesX, tileY = blockIdx.x / tilesX;
    const int x0 = tileX * TS, y0 = tileY * TS;
    const int oc0 = blockIdx.y * OCT;
    const int n = blockIdx.z;
    const int HW = H * W;

    float acc[OCT];
#pragma unroll
    for (int o = 0; o < OCT; o++) acc[o] = 0.f;

    for (int ic0 = 0; ic0 < Cin; ic0 += CIT) {
        for (int idx = tid; idx < CIT * (TS + 2) * (TS + 2); idx += 256) {
            int c  = idx / ((TS + 2) * (TS + 2));
            int r  = idx % ((TS + 2) * (TS + 2));
            int iy = r / (TS + 2), ix = r % (TS + 2);
            int gy = y0 + iy - 1, gx = x0 + ix - 1;
            int ic = ic0 + c;
            float v = 0.f;
            if (ic < Cin && gy >= 0 && gy < H && gx >= 0 && gx < W)
                v = in[(size_t)(n * Cin + ic) * HW + gy * W + gx];
            sIn[c][iy][ix] = v;
        }
        for (int idx = tid; idx < OCT * CIT * 9; idx += 256) {
            int o = idx / (CIT * 9);
            int r = idx % (CIT * 9);
            int c = r / 9, k = r % 9;
            int oc = oc0 + o, ic = ic0 + c;
            sW[o][c][k] = (oc < Cout && ic < Cin)
                              ? w[((size_t)oc * Cin + ic) * 9 + k] : 0.f;
        }
        __syncthreads();
#pragma unroll
        for (int c = 0; c < CIT; c++)
#pragma unroll
            for (int kh = 0; kh < 3; kh++)
#pragma unroll
                for (int kw = 0; kw < 3; kw++) {
                    float v = sIn[c][ty + kh][tx + kw];
#pragma unroll
                    for (int o = 0; o < OCT; o++)
                        acc[o] = fmaf(v, sW[o][c][kh * 3 + kw], acc[o]);
                }
        __syncthreads();
    }

    int gy = y0 + ty, gx = x0 + tx;
    if (gy < H && gx < W) {
#pragma unroll
        for (int o = 0; o < OCT; o++) {
            int oc = oc0 + o;
            if (oc < Cout) {
                float v = acc[o] + bias[oc];
                if (relu) v = fmaxf(v, 0.f);
                out[(size_t)(n * Cout + oc) * HW + gy * W + gx] = v;
            }
        }
    }
}

// ---------------- instance-norm stats (stem/conn/head only) ----------------
__global__ __launch_bounds__(256) void stats_kernel(
    const float* __restrict__ x, float* __restrict__ mu, float* __restrict__ rstd,
    int HW, float inv_hw)
{
    int nc = blockIdx.x;
    const float* p = x + (size_t)nc * HW;
    float s = 0.f, ss = 0.f;
    for (int i = threadIdx.x; i < HW; i += 256) {
        float v = p[i];
        s += v;
        ss = fmaf(v, v, ss);
    }
    for (int off = 32; off; off >>= 1) {
        s  += __shfl_down(s, off, 64);
        ss += __shfl_down(ss, off, 64);
    }
    __shared__ float aS[4], aSS[4];
    int wid = threadIdx.x >> 6, lane = threadIdx.x & 63;
    if (lane == 0) { aS[wid] = s; aSS[wid] = ss; }
    __syncthreads();
    if (threadIdx.x == 0) {
        s  = aS[0] + aS[1] + aS[2] + aS[3];
        ss = aSS[0] + aSS[1] + aSS[2] + aSS[3];
        float m = s * inv_hw;
        float var = fmaf(-m, m, ss * inv_hw);
        mu[nc] = m;
        rstd[nc] = rsqrtf(var + 1e-5f);
    }
}

__global__ __launch_bounds__(256) void norm_affine_relu_kernel(
    const float* __restrict__ in, float* __restrict__ out,
    const float* __restrict__ mu, const float* __restrict__ rstd,
    const float* __restrict__ g, const float* __restrict__ b,
    int C, int HW, size_t total)
{
    size_t i = (size_t)blockIdx.x * 256 + threadIdx.x;
    if (i >= total) return;
    size_t nc = i / HW;
    int c = (int)(nc % C);
    float v = (in[i] - mu[nc]) * rstd[nc] * g[c] + b[c];
    out[i] = fmaxf(v, 0.f);
}

__global__ __launch_bounds__(256) void avgpool2_kernel(
    const float* __restrict__ in, float* __restrict__ out,
    int Ho, int Wo, size_t total)
{
    size_t i = (size_t)blockIdx.x * 256 + threadIdx.x;
    if (i >= total) return;
    int wo = (int)(i % Wo);
    int ho = (int)((i / Wo) % Ho);
    size_t nc = i / ((size_t)Wo * Ho);
    const float* p = in + nc * (size_t)(4 * Ho * Wo) + (size_t)(2 * ho) * (2 * Wo) + 2 * wo;
    out[i] = 0.25f * (p[0] + p[1] + p[2 * Wo] + p[2 * Wo + 1]);
}

#define C1OCT 8
__global__ __launch_bounds__(256) void conv1x1_kernel(
    const float* __restrict__ in, const float* __restrict__ w,
    const float* __restrict__ bias, float* __restrict__ out,
    int Cin, int Cout, int HW)
{
    int p = blockIdx.x * 256 + threadIdx.x;
    int oc0 = blockIdx.y * C1OCT;
    int n = blockIdx.z;
    if (p >= HW) return;
    float acc[C1OCT];
#pragma unroll
    for (int o = 0; o < C1OCT; o++) acc[o] = 0.f;
    const float* ip = in + (size_t)n * Cin * HW + p;
    for (int ic = 0; ic < Cin; ic++) {
        float v = ip[(size_t)ic * HW];
#pragma unroll
        for (int o = 0; o < C1OCT; o++)
            acc[o] = fmaf(v, w[(size_t)(oc0 + o) * Cin + ic], acc[o]);
    }
    float* op = out + ((size_t)n * Cout + oc0) * HW + p;
#pragma unroll
    for (int o = 0; o < C1OCT; o++) op[(size_t)o * HW] = acc[o] + bias[oc0 + o];
}

__global__ __launch_bounds__(128) void head_kernel(
    const float* __restrict__ m, const float* __restrict__ hw,
    const float* __restrict__ hb, float* __restrict__ out, int C)
{
    int t = threadIdx.x;
    if (t < 80) {
        int n = t / 10, k = t % 10;
        float acc = hb[k];
        for (int c = 0; c < C; c++)
            acc = fmaf(m[n * C + c], hw[k * C + c], acc);
        out[t] = acc;
    }
}

// ---------------------------------------------------------------------------
// host orchestration
// ---------------------------------------------------------------------------
struct OdeCfg { int C, H, tilesX, gridX; };
static const OdeCfg CFG[3] = {
    {64, 96, 6, 144},    // 6 x 24 tiles (16x4)
    {128, 48, 3, 36},    // 3 x 12
    {256, 24, 2, 12},    // 2 x 6 (x-masked)
};

static void launch_c1(int st, const float* in, const unsigned short* pA,
                      const float* bias, float* sums_w, float* z, hipStream_t s)
{
    const OdeCfg& c = CFG[st];
    dim3 g(c.gridX, c.C / 32, 8);
    float ih = 1.f / (c.H * c.H);
    conv_mfma4<2, false><<<g, 128, 0, s>>>(in, pA, bias,
        nullptr, sums_w, nullptr, nullptr, z,
        c.C, c.H, c.H, c.tilesX, 8 * c.C, ih, 0, 0.f, 0.f);
}

static void launch_c2(int st, const float* z, const unsigned short* pA,
                      const float* sums_r, float* sums_z,
                      const float* ybase, float* accb, float* ydst,
                      int mode, float acoef, hipStream_t s)
{
    const OdeCfg& c = CFG[st];
    dim3 g(c.gridX, c.C / 32, 8);
    float ih = 1.f / (c.H * c.H);
    const float dt6 = 0.25f / 6.f;
    conv_mfma4<2, true><<<g, 128, 0, s>>>(z, pA, nullptr,
        sums_r, sums_z, ybase, accb, ydst,
        c.C, c.H, c.H, c.tilesX, 8 * c.C, ih, mode, acoef, dt6);
}

static void ode_block_mfma(int st, float* y, float* t, float* z, float* a,
                           float* sums, int& par, unsigned short* pack,
                           const float* bbank, hipStream_t s)
{
    const OdeCfg& c = CFG[st];
    const int C = c.C;
    const size_t BANKW = (size_t)18 * C * C;   // one bank, one dir
    const size_t DIRW  = (size_t)72 * C * C;   // 4 banks
    const float dt = 0.25f;
    for (int i = 0; i < 4; i++) {
        int j = (i + 1 > 3) ? 3 : i + 1;
        const unsigned short* p1  = pack + i * BANKW;         // dir0, bank i
        const unsigned short* p1t = pack + DIRW + i * BANKW;  // dir1, bank i
        const unsigned short* p4  = pack + j * BANKW;
        const unsigned short* p4t = pack + DIRW + j * BANKW;
        const float* b1 = bbank + (size_t)i * C;
        const float* b4 = bbank + (size_t)j * C;

        launch_c1(st, y, p1, b1, sums + par * 4096, z, s);
        launch_c2(st, z, p1t, sums + par * 4096, sums + (par ^ 1) * 4096,
                  y, a, t, 0, 0.5f * dt, s);
        par ^= 1;
        launch_c1(st, t, p1, b1, sums + par * 4096, z, s);
        launch_c2(st, z, p1t, sums + par * 4096, sums + (par ^ 1) * 4096,
                  y, a, t, 1, 0.5f * dt, s);
        par ^= 1;
        launch_c1(st, t, p1, b1, sums + par * 4096, z, s);
        launch_c2(st, z, p1t, sums + par * 4096, sums + (par ^ 1) * 4096,
                  y, a, t, 1, dt, s);
        par ^= 1;
        launch_c1(st, t, p4, b4, sums + par * 4096, z, s);
        launch_c2(st, z, p4t, sums + par * 4096, sums + (par ^ 1) * 4096,
                  y, a, y, 3, 0.f, s);
        par ^= 1;
    }
}

extern "C" void kernel_launch(void* const* d_in, const int* in_sizes, int n_in,
                              void* d_out, int out_size, void* d_ws, size_t ws_size,
                              hipStream_t stream)
{
    const float* x       = (const float*)d_in[0];
    const float* stem_w  = (const float*)d_in[1];
    const float* stem_b  = (const float*)d_in[2];
    const float* norm1_g = (const float*)d_in[3];
    const float* norm1_b = (const float*)d_in[4];
    const float* ode1_W  = (const float*)d_in[5];
    const float* ode1_b  = (const float*)d_in[6];
    const float* conn1_w = (const float*)d_in[7];
    const float* conn1_b = (const float*)d_in[8];
    const float* norm3_g = (const float*)d_in[9];
    const float* norm3_b = (const float*)d_in[10];
    const float* ode2_W  = (const float*)d_in[11];
    const float* ode2_b  = (const float*)d_in[12];
    const float* conn2_w = (const float*)d_in[13];
    const float* conn2_b = (const float*)d_in[14];
    const float* norm4_g = (const float*)d_in[15];
    const float* norm4_b = (const float*)d_in[16];
    const float* ode3_W  = (const float*)d_in[17];
    const float* ode3_b  = (const float*)d_in[18];
    const float* head_w  = (const float*)d_in[19];
    const float* head_b  = (const float*)d_in[20];
    float* out = (float*)d_out;

    float* ws = (float*)d_ws;
    const size_t BUF = 4718592; // 8*64*96*96
    float* y    = ws;
    float* t    = ws + BUF;
    float* z    = ws + 2 * BUF;
    float* a    = ws + 3 * BUF;
    float* mu   = ws + 4 * BUF;           // 2048
    float* rs   = mu + 2048;              // 2048
    float* sums = ws + 4 * BUF + 4096;    // 2 ping-pong bufs x 4096 floats
    unsigned short* pack = (unsigned short*)(ws + 4 * BUF + 4096 + 8192);

    hipMemsetAsync(sums, 0, 8192 * sizeof(float), stream);
    int par = 0;

    // ---- stem: conv3x3(3->64)+b -> IN(affine) -> relu ----
    {
        int H = 96, tiles = 6;
        dim3 grid(tiles * tiles, 64 / OCT, 8);
        conv3x3_kernel<<<grid, 256, 0, stream>>>(x, stem_w, stem_b, z,
                                                 8, 3, 64, H, H, tiles, 0);
        stats_kernel<<<8 * 64, 256, 0, stream>>>(z, mu, rs, H * H, 1.f / (H * H));
        size_t total = (size_t)8 * 64 * H * H;
        norm_affine_relu_kernel<<<(total + 255) / 256, 256, 0, stream>>>(
            z, y, mu, rs, norm1_g, norm1_b, 64, H * H, total);
    }

    // ---- ode1 ----
    {
        size_t TOT = (size_t)36 * 64 * 64;
        pack_weights<<<dim3((TOT + 255) / 256, 2), 256, 0, stream>>>(ode1_W, pack, 64);
        ode_block_mfma(0, y, t, z, a, sums, par, pack, ode1_b, stream);
    }

    // ---- conn1: 1x1(64->128) -> IN+relu -> pool ----
    {
        int H = 96, HW = H * H, Cin = 64, Cout = 128;
        dim3 grid((HW + 255) / 256, Cout / C1OCT, 8);
        conv1x1_kernel<<<grid, 256, 0, stream>>>(y, conn1_w, conn1_b, t, Cin, Cout, HW);
        stats_kernel<<<8 * Cout, 256, 0, stream>>>(t, mu, rs, HW, 1.f / HW);
        size_t total = (size_t)8 * Cout * HW;
        norm_affine_relu_kernel<<<(total + 255) / 256, 256, 0, stream>>>(
            t, t, mu, rs, norm3_g, norm3_b, Cout, HW, total);
        size_t ptotal = (size_t)8 * Cout * 48 * 48;
        avgpool2_kernel<<<(ptotal + 255) / 256, 256, 0, stream>>>(t, y, 48, 48, ptotal);
    }

    // ---- ode2 ----
    {
        size_t TOT = (size_t)36 * 128 * 128;
        pack_weights<<<dim3((TOT + 255) / 256, 2), 256, 0, stream>>>(ode2_W, pack, 128);
        ode_block_mfma(1, y, t, z, a, sums, par, pack, ode2_b, stream);
    }

    // ---- conn2: 1x1(128->256) -> IN+relu -> pool ----
    {
        int H = 48, HW = H * H, Cin = 128, Cout = 256;
        dim3 grid((HW + 255) / 256, Cout / C1OCT, 8);
        conv1x1_kernel<<<grid, 256, 0, stream>>>(y, conn2_w, conn2_b, t, Cin, Cout, HW);
        stats_kernel<<<8 * Cout, 256, 0, stream>>>(t, mu, rs, HW, 1.f / HW);
        size_t total = (size_t)8 * Cout * HW;
        norm_affine_relu_kernel<<<(total + 255) / 256, 256, 0, stream>>>(
            t, t, mu, rs, norm4_g, norm4_b, Cout, HW, total);
        size_t ptotal = (size_t)8 * Cout * 24 * 24;
        avgpool2_kernel<<<(ptotal + 255) / 256, 256, 0, stream>>>(t, y, 24, 24, ptotal);
    }

    // ---- ode3 ----
    {
        size_t TOT = (size_t)36 * 256 * 256;
        pack_weights<<<dim3((TOT + 255) / 256, 2), 256, 0, stream>>>(ode3_W, pack, 256);
        ode_block_mfma(2, y, t, z, a, sums, par, pack, ode3_b, stream);
    }

    // ---- head: GAP + linear ----
    {
        int H = 24, HW = H * H, C = 256;
        stats_kernel<<<8 * C, 256, 0, stream>>>(y, mu, rs, HW, 1.f / HW);
        head_kernel<<<1, 128, 0, stream>>>(mu, head_w, head_b, out, C);
    }
}

// Round 9
// 7031.783 us; speedup vs baseline: 1.0733x; 1.0733x over previous
//
#include <hip/hip_runtime.h>

// ---------------------------------------------------------------------------
// MPNODE_STL10 forward, round 9: round-8 core + split-bf16 z/t + XCD affinity.
//  - Base: round-8 kernel (passed). NCHW layout, fp32 y & RK4 accumulator.
//  - Change 1: z and t stored as split-bf16 u32 (low16 = hi-bf16, high16 =
//    lo-bf16). Halves z/t bytes; conv1 (k2-k4) staging becomes a raw copy of
//    the already-split pair; conv2 decodes, normalizes, re-splits.
//    State y and accb remain fp32 -> RK4 chain numerics preserved.
//  - Change 2: grid = (n(8), tile, mt), n fastest -> block linear IDs
//    round-robin over XCDs -> image n pinned to XCD n; conv1's z writes are
//    read back by conv2 from the same XCD's L2.
//  - Everything else identical to round 8 (MODE split replaces CONV2 flag).
// ---------------------------------------------------------------------------

typedef __attribute__((ext_vector_type(8)))  short  s16x8;
typedef __attribute__((ext_vector_type(16))) float  f32x16;

__device__ __forceinline__ unsigned short bf16_rtne(float f) {
    unsigned u = __builtin_bit_cast(unsigned, f);
    unsigned r = u + 0x7FFFu + ((u >> 16) & 1u);
    return (unsigned short)(r >> 16);
}
__device__ __forceinline__ void split2(float v, unsigned& h, unsigned& l) {
    unsigned u = __builtin_bit_cast(unsigned, v);
    h = (u + 0x7fffu + ((u >> 16) & 1u)) >> 16;
    float r = v - __builtin_bit_cast(float, h << 16);
    unsigned ur = __builtin_bit_cast(unsigned, r);
    l = (ur + 0x7fffu + ((ur >> 16) & 1u)) >> 16;
}
__device__ __forceinline__ unsigned packsplit(float v) {
    unsigned h, l; split2(v, h, l); return h | (l << 16);
}

// ---------------- weight pack (verified rounds 4-8) ------------------------
// Per dir (0=conv, 1=transposed+flipped), per bank(4):
//   [icc(C/16)][mt(C/32)][kp(9)][pl(2: hi,lo)][lane(64)][j(8)]
// A element: m = lane&31 -> oc, k = (lane>>5)*8+j -> ic within chunk.
__global__ __launch_bounds__(256) void pack_weights(
    const float* __restrict__ Wb, unsigned short* __restrict__ out, int C)
{
    const int dir = blockIdx.y;
    const int MT = C >> 5, ICC = C >> 4;
    const size_t TOT = (size_t)36 * C * C;
    size_t t = (size_t)blockIdx.x * 256 + threadIdx.x;
    if (t >= TOT) return;
    int j = t & 7;
    int l = (t >> 3) & 63;
    size_t r = t >> 9;
    int kp  = r % 9;  r /= 9;
    int mt  = r % MT; r /= MT;
    int icc = r % ICC; r /= ICC;
    int bank = (int)r;
    int oc = mt * 32 + (l & 31);
    int ic = icc * 16 + (l >> 5) * 8 + j;
    int kh = kp / 3, kw = kp % 3;
    float v;
    if (dir == 0)
        v = Wb[(((size_t)(bank * C + oc) * C + ic) * 3 + kh) * 3 + kw];
    else
        v = Wb[(((size_t)(bank * C + ic) * C + oc) * 3 + (2 - kh)) * 3 + (2 - kw)];
    unsigned short h = bf16_rtne(v);
    float hf = __builtin_bit_cast(float, (unsigned)h << 16);
    unsigned short lo = bf16_rtne(v - hf);
    size_t idx = ((((size_t)bank * ICC + icc) * MT + mt) * 9 + kp) * 1024 + l * 8 + j;
    unsigned short* base = out + (size_t)dir * 72 * C * C;
    base[idx] = h;
    base[idx + 512] = lo;
}

// ---------------- MFMA conv kernel -----------------------------------------
// MODE 0: conv1, fp32 input (k1 stages from y)
// MODE 1: conv1, split-u32 input (k2-k4 stage from t; raw copy)
// MODE 2: conv2, split-u32 input (z) + instnorm; RK4 epilogue
template<int NW, int MODE>
__global__ __launch_bounds__(NW * 64) void conv_mfma4(
    const void* __restrict__ in,
    const unsigned short* __restrict__ pA,
    const float* __restrict__ bias,
    const float* __restrict__ sums_in,       // conv2: [s | ss], 2*NCtot floats
    float* __restrict__ sums_out,            // conv1: accumulate; conv2: zero
    const float* __restrict__ ybase, float* __restrict__ accb,
    float* __restrict__ ydstF, unsigned* __restrict__ ydstS,
    int C, int H, int W, int tilesX, int NCtot, float inv_hw,
    int mode, float acoef, float dt6)
{
    constexpr bool CONV2 = (MODE == 2);
    constexpr int TPX = 16, TPY = 2 * NW;
    constexpr int HX = TPX + 2, HY = TPY + 2;
    constexpr int NROW = HX * HY;
    constexpr int RS = 20;               // row stride (shorts), 40B
    constexpr int PL = NROW * RS;
    constexpr int BUFS = 2 * PL;         // hi plane + lo plane
    constexpr int NTHR = NW * 64;
    constexpr int NELEM = NROW * 16;
    constexpr int NIT = (NELEM + NTHR - 1) / NTHR;
    __shared__ __align__(16) unsigned short sB[2 * BUFS];
    __shared__ float sTab[CONV2 ? 512 : 4];

    const int tid = threadIdx.x;
    const int w = tid >> 6, lane = tid & 63;
    const int n = blockIdx.x;            // fastest dim -> image n on XCD n
    const int tile = blockIdx.y;
    const int mt = blockIdx.z;
    const int tileX = tile % tilesX, tileY = tile / tilesX;
    const int px0 = tileX * TPX, py0 = tileY * TPY;
    const int ocb = mt * 32;
    const int HW = H * W;
    const int ICC = C >> 4, MT = C >> 5;
    const int col = lane & 31, half = lane >> 5;
    const int xl = col & 15, yr = col >> 4;
    const int wy0 = 2 * w;
    const int ncbase = n * C;

    // conv2: zero the *other* ping-pong sum buffer for the next conv1
    if (CONV2 && blockIdx.x == 0 && blockIdx.y == 0) {
        int per = (2 * NCtot + MT - 1) / MT;
        int st = mt * per;
        int en = st + per; if (en > 2 * NCtot) en = 2 * NCtot;
        for (int i = st + tid; i < en; i += NTHR) sums_out[i] = 0.f;
    }
    // conv2: per-channel mu/rstd table for this n (one rsqrt per channel)
    if (CONV2) {
        for (int c0 = tid; c0 < C; c0 += NTHR) {
            float s = sums_in[ncbase + c0];
            float q = sums_in[NCtot + ncbase + c0];
            float m = s * inv_hw;
            sTab[2 * c0] = m;
            sTab[2 * c0 + 1] = rsqrtf(fmaf(-m, m, q * inv_hw) + 1e-5f);
        }
        __syncthreads();
    }

    float stg[NIT];
    auto stageLoad = [&](int icc) {
#pragma unroll
        for (int i = 0; i < NIT; i++) {
            int e = tid + i * NTHR;
            float v = 0.f;
            if (e < NELEM) {
                int ic = e / NROW; int r = e - ic * NROW;
                int yy = r / HX, xx = r - yy * HX;
                int gy = py0 + yy - 1, gx = px0 + xx - 1;
                if (gy >= 0 && gy < H && gx >= 0 && gx < W) {
                    int c = icc * 16 + ic;
                    size_t ad = (size_t)(ncbase + c) * HW + gy * W + gx;
                    if (MODE == 0) {
                        v = ((const float*)in)[ad];
                    } else if (MODE == 1) {
                        v = __builtin_bit_cast(float, ((const unsigned*)in)[ad]);
                    } else {
                        unsigned u = ((const unsigned*)in)[ad];
                        float vh = __builtin_bit_cast(float, u << 16);
                        float vl = __builtin_bit_cast(float, u & 0xffff0000u);
                        v = (vh + vl - sTab[2 * c]) * sTab[2 * c + 1];
                    }
                }
            }
            stg[i] = v;
        }
    };
    auto stageWrite = [&](int b) {
#pragma unroll
        for (int i = 0; i < NIT; i++) {
            int e = tid + i * NTHR;
            if (e < NELEM) {
                int ic = e / NROW; int r = e - ic * NROW;
                unsigned h, l;
                if (MODE == 1) {
                    unsigned u = __builtin_bit_cast(unsigned, stg[i]);
                    h = u & 0xffffu; l = u >> 16;
                } else {
                    split2(stg[i], h, l);
                }
                int off = b * BUFS + r * RS + ic;
                sB[off] = (unsigned short)h;
                sB[off + PL] = (unsigned short)l;
            }
        }
    };
    auto loadB = [&](int b, int kp, s16x8& oh, s16x8& ol) {
        int kh = kp / 3, kw = kp - kh * 3;
        int px = (wy0 + yr + kh) * HX + (xl + kw);
        int off = b * BUFS + px * RS + half * 8;
        oh = *(const s16x8*)&sB[off];
        ol = *(const s16x8*)&sB[off + PL];
    };

    f32x16 accA{}, accB{}, accC{};

    stageLoad(0);
    stageWrite(0);
    __syncthreads();

    for (int icc = 0; icc < ICC; ++icc) {
        // ---- bulk A loads: whole chunk's 9 kp hi+lo into regs ----
        s16x8 aH[9], aL[9];
        {
            const unsigned short* ab =
                pA + ((size_t)(icc * MT + mt)) * 9216 + lane * 8;
#pragma unroll
            for (int kp = 0; kp < 9; ++kp) {
                aH[kp] = *(const s16x8*)(ab + kp * 1024);
                aL[kp] = *(const s16x8*)(ab + kp * 1024 + 512);
            }
        }
        const int b = icc & 1;
        if (icc + 1 < ICC) stageLoad(icc + 1);   // stays outstanding over MFMAs

        s16x8 bh, bl;
        loadB(b, 0, bh, bl);
#pragma unroll
        for (int kp = 0; kp < 9; ++kp) {
            s16x8 bhn, bln;
            if (kp < 8) loadB(b, kp + 1, bhn, bln);
            accA = __builtin_amdgcn_mfma_f32_32x32x16_bf16(aH[kp], bh, accA, 0, 0, 0);
            accB = __builtin_amdgcn_mfma_f32_32x32x16_bf16(aL[kp], bh, accB, 0, 0, 0);
            accC = __builtin_amdgcn_mfma_f32_32x32x16_bf16(aH[kp], bl, accC, 0, 0, 0);
            if (kp < 8) { bh = bhn; bl = bln; }
        }
        if (icc + 1 < ICC) {
            stageWrite(b ^ 1);
            __syncthreads();
        }
    }

    // ---- epilogue: C/D layout col=lane&31, row=(r&3)+8*(r>>2)+4*half ----
    // n-mapping: x = col&15, y = col>>4 -> full 64B-line coalescing.
    const int gx = px0 + xl;
    const int gy = py0 + wy0 + yr;
    const bool valid = (gx < W);
    float* sred = (float*)sB;   // last chunk used buffer 1; buffer 0 free
#pragma unroll
    for (int r = 0; r < 16; r++) {
        int row = (r & 3) + 8 * (r >> 2) + 4 * half;
        int oc = ocb + row;
        size_t idx = (size_t)(ncbase + oc) * HW + (size_t)gy * W + gx;
        float v = accA[r] + accB[r] + accC[r];
        if (!CONV2) {
            v += bias[oc];
            v = fmaxf(v, 0.f);
            if (valid) ydstS[idx] = packsplit(v);      // z, split-u32
            float s = valid ? v : 0.f;
            float sq = s * s;
#pragma unroll
            for (int m = 1; m < 32; m <<= 1) {
                s  += __shfl_xor(s, m, 64);
                sq += __shfl_xor(sq, m, 64);
            }
            if ((lane & 31) == 0) {
                int slot = ((w * 2 + half) * 16 + r) * 2;
                sred[slot] = s;
                sred[slot + 1] = sq;
            }
        } else if (valid) {
            float k = -v;
            if (mode == 0) {
                accb[idx] = k;
                ydstS[idx] = packsplit(ybase[idx] + acoef * k);   // t
            } else if (mode == 3) {
                ydstF[idx] = ybase[idx] + dt6 * (accb[idx] + k);  // y, fp32
            } else {
                accb[idx] += 2.f * k;
                ydstS[idx] = packsplit(ybase[idx] + acoef * k);   // t
            }
        }
    }
    if (!CONV2) {
        __syncthreads();
        if (tid < 32) {
            int h2 = (tid >> 2) & 1;
            int r  = (tid & 3) | ((tid >> 3) << 2);
            float s = 0.f, sq = 0.f;
#pragma unroll
            for (int wv = 0; wv < NW; wv++) {
                int slot = ((wv * 2 + h2) * 16 + r) * 2;
                s  += sred[slot];
                sq += sred[slot + 1];
            }
            atomicAdd(&sums_out[ncbase + ocb + tid], s);
            atomicAdd(&sums_out[NCtot + ncbase + ocb + tid], sq);
        }
    }
}

// ---------------- fp32 stem conv (Cin=3) -----------------------------------
#define TS  16
#define OCT 16
#define CIT 8
__global__ __launch_bounds__(256) void conv3x3_kernel(
    const float* __restrict__ in, const float* __restrict__ w,
    const float* __restrict__ bias, float* __restrict__ out,
    int N, int Cin, int Cout, int H, int W, int tilesX, int relu)
{
    __shared__ float sIn[CIT][TS + 2][TS + 2];
    __shared__ float sW[OCT][CIT][9];
    const int tid = threadIdx.x;
    const int tx = tid & (TS - 1), ty = tid >> 4;
    const int tileX = blockIdx.x % tilesX, tileY = blockIdx.x / tilesX;
    const int x0 = tileX * TS, y0 = tileY * TS;
    const int oc0 = blockIdx.y * OCT;
    const int n = blockIdx.z;
    const int HW = H * W;

    float acc[OCT];
#pragma unroll
    for (int o = 0; o < OCT; o++) acc[o] = 0.f;

    for (int ic0 = 0; ic0 < Cin; ic0 += CIT) {
        for (int idx = tid; idx < CIT * (TS + 2) * (TS + 2); idx += 256) {
            int c  = idx / ((TS + 2) * (TS + 2));
            int r  = idx % ((TS + 2) * (TS + 2));
            int iy = r / (TS + 2), ix = r % (TS + 2);
            int gy = y0 + iy - 1, gx = x0 + ix - 1;
            int ic = ic0 + c;
            float v = 0.f;
            if (ic < Cin && gy >= 0 && gy < H && gx >= 0 && gx < W)
                v = in[(size_t)(n * Cin + ic) * HW + gy * W + gx];
            sIn[c][iy][ix] = v;
        }
        for (int idx = tid; idx < OCT * CIT * 9; idx += 256) {
            int o = idx / (CIT * 9);
            int r = idx % (CIT * 9);
            int c = r / 9, k = r % 9;
            int oc = oc0 + o, ic = ic0 + c;
            sW[o][c][k] = (oc < Cout && ic < Cin)
                              ? w[((size_t)oc * Cin + ic) * 9 + k] : 0.f;
        }
        __syncthreads();
#pragma unroll
        for (int c = 0; c < CIT; c++)
#pragma unroll
            for (int kh = 0; kh < 3; kh++)
#pragma unroll
                for (int kw = 0; kw < 3; kw++) {
                    float v = sIn[c][ty + kh][tx + kw];
#pragma unroll
                    for (int o = 0; o < OCT; o++)
                        acc[o] = fmaf(v, sW[o][c][kh * 3 + kw], acc[o]);
                }
        __syncthreads();
    }

    int gy = y0 + ty, gx = x0 + tx;
    if (gy < H && gx < W) {
#pragma unroll
        for (int o = 0; o < OCT; o++) {
            int oc = oc0 + o;
            if (oc < Cout) {
                float v = acc[o] + bias[oc];
                if (relu) v = fmaxf(v, 0.f);
                out[(size_t)(n * Cout + oc) * HW + gy * W + gx] = v;
            }
        }
    }
}

// ---------------- instance-norm stats (stem/conn/head only) ----------------
__global__ __launch_bounds__(256) void stats_kernel(
    const float* __restrict__ x, float* __restrict__ mu, float* __restrict__ rstd,
    int HW, float inv_hw)
{
    int nc = blockIdx.x;
    const float* p = x + (size_t)nc * HW;
    float s = 0.f, ss = 0.f;
    for (int i = threadIdx.x; i < HW; i += 256) {
        float v = p[i];
        s += v;
        ss = fmaf(v, v, ss);
    }
    for (int off = 32; off; off >>= 1) {
        s  += __shfl_down(s, off, 64);
        ss += __shfl_down(ss, off, 64);
    }
    __shared__ float aS[4], aSS[4];
    int wid = threadIdx.x >> 6, lane = threadIdx.x & 63;
    if (lane == 0) { aS[wid] = s; aSS[wid] = ss; }
    __syncthreads();
    if (threadIdx.x == 0) {
        s  = aS[0] + aS[1] + aS[2] + aS[3];
        ss = aSS[0] + aSS[1] + aSS[2] + aSS[3];
        float m = s * inv_hw;
        float var = fmaf(-m, m, ss * inv_hw);
        mu[nc] = m;
        rstd[nc] = rsqrtf(var + 1e-5f);
    }
}

__global__ __launch_bounds__(256) void norm_affine_relu_kernel(
    const float* __restrict__ in, float* __restrict__ out,
    const float* __restrict__ mu, const float* __restrict__ rstd,
    const float* __restrict__ g, const float* __restrict__ b,
    int C, int HW, size_t total)
{
    size_t i = (size_t)blockIdx.x * 256 + threadIdx.x;
    if (i >= total) return;
    size_t nc = i / HW;
    int c = (int)(nc % C);
    float v = (in[i] - mu[nc]) * rstd[nc] * g[c] + b[c];
    out[i] = fmaxf(v, 0.f);
}

__global__ __launch_bounds__(256) void avgpool2_kernel(
    const float* __restrict__ in, float* __restrict__ out,
    int Ho, int Wo, size_t total)
{
    size_t i = (size_t)blockIdx.x * 256 + threadIdx.x;
    if (i >= total) return;
    int wo = (int)(i % Wo);
    int ho = (int)((i / Wo) % Ho);
    size_t nc = i / ((size_t)Wo * Ho);
    const float* p = in + nc * (size_t)(4 * Ho * Wo) + (size_t)(2 * ho) * (2 * Wo) + 2 * wo;
    out[i] = 0.25f * (p[0] + p[1] + p[2 * Wo] + p[2 * Wo + 1]);
}

#define C1OCT 8
__global__ __launch_bounds__(256) void conv1x1_kernel(
    const float* __restrict__ in, const float* __restrict__ w,
    const float* __restrict__ bias, float* __restrict__ out,
    int Cin, int Cout, int HW)
{
    int p = blockIdx.x * 256 + threadIdx.x;
    int oc0 = blockIdx.y * C1OCT;
    int n = blockIdx.z;
    if (p >= HW) return;
    float acc[C1OCT];
#pragma unroll
    for (int o = 0; o < C1OCT; o++) acc[o] = 0.f;
    const float* ip = in + (size_t)n * Cin * HW + p;
    for (int ic = 0; ic < Cin; ic++) {
        float v = ip[(size_t)ic * HW];
#pragma unroll
        for (int o = 0; o < C1OCT; o++)
            acc[o] = fmaf(v, w[(size_t)(oc0 + o) * Cin + ic], acc[o]);
    }
    float* op = out + ((size_t)n * Cout + oc0) * HW + p;
#pragma unroll
    for (int o = 0; o < C1OCT; o++) op[(size_t)o * HW] = acc[o] + bias[oc0 + o];
}

__global__ __launch_bounds__(128) void head_kernel(
    const float* __restrict__ m, const float* __restrict__ hw,
    const float* __restrict__ hb, float* __restrict__ out, int C)
{
    int t = threadIdx.x;
    if (t < 80) {
        int n = t / 10, k = t % 10;
        float acc = hb[k];
        for (int c = 0; c < C; c++)
            acc = fmaf(m[n * C + c], hw[k * C + c], acc);
        out[t] = acc;
    }
}

// ---------------------------------------------------------------------------
// host orchestration
// ---------------------------------------------------------------------------
struct OdeCfg { int C, H, tilesX, tilesT; };
static const OdeCfg CFG[3] = {
    {64, 96, 6, 144},    // 6 x 24 tiles (16x4)
    {128, 48, 3, 36},    // 3 x 12
    {256, 24, 2, 12},    // 2 x 6 (x-masked)
};

static void launch_c1(int st, int inMode, const void* in, const unsigned short* pA,
                      const float* bias, float* sums_w, unsigned* z, hipStream_t s)
{
    const OdeCfg& c = CFG[st];
    dim3 g(8, c.tilesT, c.C / 32);   // n fastest -> image n on XCD n
    float ih = 1.f / (c.H * c.H);
    if (inMode == 0)
        conv_mfma4<2, 0><<<g, 128, 0, s>>>(in, pA, bias,
            nullptr, sums_w, nullptr, nullptr, nullptr, z,
            c.C, c.H, c.H, c.tilesX, 8 * c.C, ih, 0, 0.f, 0.f);
    else
        conv_mfma4<2, 1><<<g, 128, 0, s>>>(in, pA, bias,
            nullptr, sums_w, nullptr, nullptr, nullptr, z,
            c.C, c.H, c.H, c.tilesX, 8 * c.C, ih, 0, 0.f, 0.f);
}

static void launch_c2(int st, const unsigned* z, const unsigned short* pA,
                      const float* sums_r, float* sums_z,
                      const float* ybase, float* accb,
                      float* ydstF, unsigned* ydstS,
                      int mode, float acoef, hipStream_t s)
{
    const OdeCfg& c = CFG[st];
    dim3 g(8, c.tilesT, c.C / 32);
    float ih = 1.f / (c.H * c.H);
    const float dt6 = 0.25f / 6.f;
    conv_mfma4<2, 2><<<g, 128, 0, s>>>(z, pA, nullptr,
        sums_r, sums_z, ybase, accb, ydstF, ydstS,
        c.C, c.H, c.H, c.tilesX, 8 * c.C, ih, mode, acoef, dt6);
}

static void ode_block_mfma(int st, float* y, unsigned* t, unsigned* z, float* a,
                           float* sums, int& par, unsigned short* pack,
                           const float* bbank, hipStream_t s)
{
    const OdeCfg& c = CFG[st];
    const int C = c.C;
    const size_t BANKW = (size_t)18 * C * C;   // one bank, one dir
    const size_t DIRW  = (size_t)72 * C * C;   // 4 banks
    const float dt = 0.25f;
    for (int i = 0; i < 4; i++) {
        int j = (i + 1 > 3) ? 3 : i + 1;
        const unsigned short* p1  = pack + i * BANKW;         // dir0, bank i
        const unsigned short* p1t = pack + DIRW + i * BANKW;  // dir1, bank i
        const unsigned short* p4  = pack + j * BANKW;
        const unsigned short* p4t = pack + DIRW + j * BANKW;
        const float* b1 = bbank + (size_t)i * C;
        const float* b4 = bbank + (size_t)j * C;

        // k1 (from fp32 y)
        launch_c1(st, 0, y, p1, b1, sums + par * 4096, z, s);
        launch_c2(st, z, p1t, sums + par * 4096, sums + (par ^ 1) * 4096,
                  y, a, nullptr, t, 0, 0.5f * dt, s);
        par ^= 1;
        // k2 (from split t)
        launch_c1(st, 1, t, p1, b1, sums + par * 4096, z, s);
        launch_c2(st, z, p1t, sums + par * 4096, sums + (par ^ 1) * 4096,
                  y, a, nullptr, t, 1, 0.5f * dt, s);
        par ^= 1;
        // k3
        launch_c1(st, 1, t, p1, b1, sums + par * 4096, z, s);
        launch_c2(st, z, p1t, sums + par * 4096, sums + (par ^ 1) * 4096,
                  y, a, nullptr, t, 1, dt, s);
        par ^= 1;
        // k4 + update (y out, fp32)
        launch_c1(st, 1, t, p4, b4, sums + par * 4096, z, s);
        launch_c2(st, z, p4t, sums + par * 4096, sums + (par ^ 1) * 4096,
                  y, a, y, t, 3, 0.f, s);
        par ^= 1;
    }
}

extern "C" void kernel_launch(void* const* d_in, const int* in_sizes, int n_in,
                              void* d_out, int out_size, void* d_ws, size_t ws_size,
                              hipStream_t stream)
{
    const float* x       = (const float*)d_in[0];
    const float* stem_w  = (const float*)d_in[1];
    const float* stem_b  = (const float*)d_in[2];
    const float* norm1_g = (const float*)d_in[3];
    const float* norm1_b = (const float*)d_in[4];
    const float* ode1_W  = (const float*)d_in[5];
    const float* ode1_b  = (const float*)d_in[6];
    const float* conn1_w = (const float*)d_in[7];
    const float* conn1_b = (const float*)d_in[8];
    const float* norm3_g = (const float*)d_in[9];
    const float* norm3_b = (const float*)d_in[10];
    const float* ode2_W  = (const float*)d_in[11];
    const float* ode2_b  = (const float*)d_in[12];
    const float* conn2_w = (const float*)d_in[13];
    const float* conn2_b = (const float*)d_in[14];
    const float* norm4_g = (const float*)d_in[15];
    const float* norm4_b = (const float*)d_in[16];
    const float* ode3_W  = (const float*)d_in[17];
    const float* ode3_b  = (const float*)d_in[18];
    const float* head_w  = (const float*)d_in[19];
    const float* head_b  = (const float*)d_in[20];
    float* out = (float*)d_out;

    float* ws = (float*)d_ws;
    const size_t BUF = 4718592; // 8*64*96*96 elements
    float*    y  = ws;
    unsigned* t  = (unsigned*)(ws + BUF);     // split-bf16 state t / conn scratch
    unsigned* z  = (unsigned*)(ws + 2 * BUF); // split-bf16 activations z
    float*    a  = ws + 3 * BUF;              // fp32 RK4 accumulator
    float*    mu = ws + 4 * BUF;              // 2048
    float*    rs = mu + 2048;                 // 2048
    float*    sums = ws + 4 * BUF + 4096;     // 2 ping-pong bufs x 4096 floats
    unsigned short* pack = (unsigned short*)(ws + 4 * BUF + 4096 + 8192);
    float* tf = (float*)t;                    // conn scratch reuse (fp32)

    hipMemsetAsync(sums, 0, 8192 * sizeof(float), stream);
    int par = 0;

    // ---- stem: conv3x3(3->64)+b -> IN(affine) -> relu ----
    {
        int H = 96, tiles = 6;
        dim3 grid(tiles * tiles, 64 / OCT, 8);
        conv3x3_kernel<<<grid, 256, 0, stream>>>(x, stem_w, stem_b, (float*)z,
                                                 8, 3, 64, H, H, tiles, 0);
        stats_kernel<<<8 * 64, 256, 0, stream>>>((float*)z, mu, rs, H * H, 1.f / (H * H));
        size_t total = (size_t)8 * 64 * H * H;
        norm_affine_relu_kernel<<<(total + 255) / 256, 256, 0, stream>>>(
            (float*)z, y, mu, rs, norm1_g, norm1_b, 64, H * H, total);
    }

    // ---- ode1 ----
    {
        size_t TOT = (size_t)36 * 64 * 64;
        pack_weights<<<dim3((TOT + 255) / 256, 2), 256, 0, stream>>>(ode1_W, pack, 64);
        ode_block_mfma(0, y, t, z, a, sums, par, pack, ode1_b, stream);
    }

    // ---- conn1: 1x1(64->128) -> IN+relu -> pool ----
    {
        int H = 96, HW = H * H, Cin = 64, Cout = 128;
        dim3 grid((HW + 255) / 256, Cout / C1OCT, 8);
        conv1x1_kernel<<<grid, 256, 0, stream>>>(y, conn1_w, conn1_b, tf, Cin, Cout, HW);
        stats_kernel<<<8 * Cout, 256, 0, stream>>>(tf, mu, rs, HW, 1.f / HW);
        size_t total = (size_t)8 * Cout * HW;
        norm_affine_relu_kernel<<<(total + 255) / 256, 256, 0, stream>>>(
            tf, tf, mu, rs, norm3_g, norm3_b, Cout, HW, total);
        size_t ptotal = (size_t)8 * Cout * 48 * 48;
        avgpool2_kernel<<<(ptotal + 255) / 256, 256, 0, stream>>>(tf, y, 48, 48, ptotal);
    }

    // ---- ode2 ----
    {
        size_t TOT = (size_t)36 * 128 * 128;
        pack_weights<<<dim3((TOT + 255) / 256, 2), 256, 0, stream>>>(ode2_W, pack, 128);
        ode_block_mfma(1, y, t, z, a, sums, par, pack, ode2_b, stream);
    }

    // ---- conn2: 1x1(128->256) -> IN+relu -> pool ----
    {
        int H = 48, HW = H * H, Cin = 128, Cout = 256;
        dim3 grid((HW + 255) / 256, Cout / C1OCT, 8);
        conv1x1_kernel<<<grid, 256, 0, stream>>>(y, conn2_w, conn2_b, tf, Cin, Cout, HW);
        stats_kernel<<<8 * Cout, 256, 0, stream>>>(tf, mu, rs, HW, 1.f / HW);
        size_t total = (size_t)8 * Cout * HW;
        norm_affine_relu_kernel<<<(total + 255) / 256, 256, 0, stream>>>(
            tf, tf, mu, rs, norm4_g, norm4_b, Cout, HW, total);
        size_t ptotal = (size_t)8 * Cout * 24 * 24;
        avgpool2_kernel<<<(ptotal + 255) / 256, 256, 0, stream>>>(tf, y, 24, 24, ptotal);
    }

    // ---- ode3 ----
    {
        size_t TOT = (size_t)36 * 256 * 256;
        pack_weights<<<dim3((TOT + 255) / 256, 2), 256, 0, stream>>>(ode3_W, pack, 256);
        ode_block_mfma(2, y, t, z, a, sums, par, pack, ode3_b, stream);
    }

    // ---- head: GAP + linear ----
    {
        int H = 24, HW = H * H, C = 256;
        stats_kernel<<<8 * C, 256, 0, stream>>>(y, mu, rs, HW, 1.f / HW);
        head_kernel<<<1, 128, 0, stream>>>(mu, head_w, head_b, out, C);
    }
}